// Round 1
// 462.637 us; speedup vs baseline: 1.0324x; 1.0324x over previous
//
#include <hip/hip_runtime.h>
#include <math.h>

#define LL 2
#define BB 32
#define SS 2048
#define HH 512
#define DD 1024      // 2*H
#define W4S 2048     // attn_w row stride = 4*H

// fused scores kernel tiling
#define BM 128
#define BN 512       // full H in one block -> complete score rows locally
#define BK 64
#define NT (DD / BK)     // 16 k-tiles
#define ASTR 72          // A LDS row stride in shorts (144 B = 9*16)

typedef __attribute__((ext_vector_type(8))) short bf16x8;
typedef __attribute__((ext_vector_type(4))) float f32x4;

// fp32 pair -> packed bf16x2, round-to-nearest-even (one-time pack)
__device__ inline unsigned pk2_rne(float a, float b) {
    unsigned ua = __float_as_uint(a), ub = __float_as_uint(b);
    unsigned ra = (ua + 0x7fffu + ((ua >> 16) & 1u)) >> 16;
    unsigned rb = (ub + 0x7fffu + ((ub >> 16) & 1u)) & 0xffff0000u;
    return ra | rb;
}

// fp32 pair -> packed bf16x2, round-half-up: 2 adds + v_perm
__device__ inline unsigned pk2_hu(float a, float b) {
    unsigned ua = __float_as_uint(a) + 0x8000u;
    unsigned ub = __float_as_uint(b) + 0x8000u;
    return __builtin_amdgcn_perm(ub, ua, 0x07060302u);
}

__device__ inline float fast_tanh(float x) {
    x = fminf(9.f, fmaxf(-9.f, x));
    float e = __expf(2.f * x);
    return 1.f - 2.f * __builtin_amdgcn_rcpf(e + 1.f);
}

// async global->LDS, 16 B per lane; LDS dest = base + lane*16
__device__ inline void gl_lds16(const unsigned short* g, short* l) {
    __builtin_amdgcn_global_load_lds(
        (const __attribute__((address_space(1))) unsigned int*)g,
        (__attribute__((address_space(3))) unsigned int*)l, 16, 0, 0);
}

// ---------------- one-time pack: w_e fp32 -> bf16 row-major [HH][DD] ---------
// also zeros the per-batch softmax denominators
__global__ __launch_bounds__(256) void k_pack(const float* __restrict__ attn_w,
                                              unsigned short* __restrict__ Bp,
                                              float* __restrict__ den) {
    int h = blockIdx.x, t = threadIdx.x;
    if (h == 0 && t < BB) den[t] = 0.f;
    float4 v = *(const float4*)(attn_w + (size_t)h * W4S + DD + t * 4);
    uint2 r = make_uint2(pk2_rne(v.x, v.y), pk2_rne(v.z, v.w));
    *(uint2*)(Bp + (size_t)h * DD + t * 4) = r;
}

// ---------------- base[b,h] = dot(hidden[-1,b,:], w_h[h,:]) + bias[h] --------
__global__ __launch_bounds__(256) void k_base(const float* __restrict__ hidden,
                                              const float* __restrict__ attn_w,
                                              const float* __restrict__ attn_b,
                                              float* __restrict__ base) {
    int wid  = (blockIdx.x * 256 + threadIdx.x) >> 6;
    int lane = threadIdx.x & 63;
    int b = wid >> 9;
    int h = wid & (HH - 1);
    const float4* h4 = (const float4*)(hidden + (size_t)(LL - 1) * BB * DD + (size_t)b * DD);
    const float4* w4 = (const float4*)(attn_w + (size_t)h * W4S);
    float s = 0.f;
    #pragma unroll
    for (int i = 0; i < 4; i++) {
        float4 a = h4[lane + i * 64], w = w4[lane + i * 64];
        s += a.x * w.x + a.y * w.y + a.z * w.z + a.w * w.w;
    }
    #pragma unroll
    for (int off = 32; off; off >>= 1) s += __shfl_xor(s, off);
    if (lane == 0) base[b * HH + h] = s + attn_b[h];
}

// ---------------- fused GEMM + tanh + exp + context partial ------------------
// Per block: 128 enc rows x full H. C = enc*w_e^T; s_m = sum_n v_n*tanh(C+base);
// e_m = exp(s_m) (no row-max: |s| <= sum|v| ~ 18, safe in fp32);
// den[b] += sum e; part[2*bx+half][:] = sum_m e_m * enc[m][:]
__global__ __launch_bounds__(512, 2) void k_scores(const float* __restrict__ enc,
                                                   const unsigned short* __restrict__ Bp,
                                                   const float* __restrict__ base,
                                                   const float* __restrict__ vw,
                                                   float* __restrict__ den,
                                                   float* __restrict__ part,
                                                   float* __restrict__ attn_out) {
    __shared__ short As[BM * ASTR];     // 18432 B, padded rows
    __shared__ short Bs[2][BN * BK];    // 2 x 64 KB, granule-XOR swizzled

    const int tid  = threadIdx.x;
    const int wid  = tid >> 6;
    const int lane = tid & 63;
    const int lm   = lane & 15;
    const int kq   = lane >> 4;
    const int wr   = wid >> 2;                 // 0..1  (m-slice of 64)
    const int wc   = wid & 3;                  // 0..3  (n-slice of 128)
    const int m0   = blockIdx.x * BM;
    const int b    = m0 >> 11;
    const int srow = m0 & (SS - 1);
    const int wn   = wid * 64;                 // B-staging slice (8 waves x 64 rows)

    // A staging: thread handles bf16 granules -> rows tid>>3 and tid>>3+64
    const int rowA = tid >> 3;                 // 0..63
    const int gA   = tid & 7;
    const float* Ag0 = enc + (size_t)(m0 + rowA) * DD + gA * 8;
    const float* Ag1 = Ag0 + (size_t)64 * DD;
    short* AsW0 = As + rowA * ASTR + gA * 8;
    short* AsW1 = AsW0 + 64 * ASTR;

    // B staging via global_load_lds: wave covers rows wn..wn+63, 8 instrs of 8 rows.
    // LDS granule (row, g) holds global granule g ^ (row&7)  (read-side swizzle).
    const int brow = lane >> 3;
    const int bgsw = (lane & 7) ^ brow;
    const unsigned short* Bg = Bp + (size_t)(wn + brow) * DD + bgsw * 8;

    f32x4 acc[4][8];
    #pragma unroll
    for (int i = 0; i < 4; i++)
        #pragma unroll
        for (int j = 0; j < 8; j++) acc[i][j] = (f32x4){0.f, 0.f, 0.f, 0.f};

    // ---- prologue: issue B(0) + A(0) loads ----
    #pragma unroll
    for (int i = 0; i < 8; i++)
        gl_lds16(Bg + (size_t)(i * 8) * DD, &Bs[0][(wn + i * 8) * BK]);
    float4 a0 = *(const float4*)(Ag0);
    float4 a1 = *(const float4*)(Ag0 + 4);
    float4 a2 = *(const float4*)(Ag1);
    float4 a3 = *(const float4*)(Ag1 + 4);

    for (int kt = 0; kt < NT; kt++) {
        __syncthreads();   // prev readers of As done; drains A(kt)/B(kt) loads
        uint4 p0 = {pk2_hu(a0.x, a0.y), pk2_hu(a0.z, a0.w),
                    pk2_hu(a1.x, a1.y), pk2_hu(a1.z, a1.w)};
        uint4 p1 = {pk2_hu(a2.x, a2.y), pk2_hu(a2.z, a2.w),
                    pk2_hu(a3.x, a3.y), pk2_hu(a3.z, a3.w)};
        *(uint4*)AsW0 = p0;
        *(uint4*)AsW1 = p1;
        __syncthreads();   // As(kt) visible
        if (kt + 1 < NT) { // prefetch kt+1 (in flight across MFMA below)
            #pragma unroll
            for (int i = 0; i < 8; i++)
                gl_lds16(Bg + (size_t)(i * 8) * DD + (kt + 1) * BK,
                         &Bs[(kt + 1) & 1][(wn + i * 8) * BK]);
            a0 = *(const float4*)(Ag0 + (kt + 1) * BK);
            a1 = *(const float4*)(Ag0 + (kt + 1) * BK + 4);
            a2 = *(const float4*)(Ag1 + (kt + 1) * BK);
            a3 = *(const float4*)(Ag1 + (kt + 1) * BK + 4);
        }
        const short* Bb = Bs[kt & 1];
        #pragma unroll
        for (int s = 0; s < 2; s++) {
            bf16x8 af[4];
            #pragma unroll
            for (int mi = 0; mi < 4; mi++)
                af[mi] = *(const bf16x8*)&As[(wr * 64 + mi * 16 + lm) * ASTR + (s * 4 + kq) * 8];
            #pragma unroll
            for (int ni = 0; ni < 8; ni++) {
                bf16x8 bf = *(const bf16x8*)
                    &Bb[(wc * 128 + ni * 16 + lm) * BK + (((s * 4 + kq)) ^ (lm & 7)) * 8];
                #pragma unroll
                for (int mi = 0; mi < 4; mi++)
                    acc[mi][ni] = __builtin_amdgcn_mfma_f32_16x16x32_bf16(
                        af[mi], bf, acc[mi][ni], 0, 0, 0);
            }
        }
    }

    // ---- epilogue: scores -> exp -> den atomic -> context partial ----
    __syncthreads();                     // done with As: reuse as reduction space
    float* red  = (float*)As;            // [4][128]
    float* esh  = red + 4 * BM;          // [128]
    float* dsum = esh + BM;              // [2]

    const float* basep = base + b * HH + wc * 128;
    const float* vp    = vw + wc * 128;
    float p[4][4] = {};
    #pragma unroll
    for (int ni = 0; ni < 8; ni++) {
        int nl = ni * 16 + lm;
        float bs = basep[nl];
        float vv = vp[nl];
        #pragma unroll
        for (int mi = 0; mi < 4; mi++)
            #pragma unroll
            for (int r = 0; r < 4; r++)
                p[mi][r] += vv * fast_tanh(acc[mi][ni][r] + bs);
    }
    #pragma unroll
    for (int off = 8; off; off >>= 1)
        #pragma unroll
        for (int mi = 0; mi < 4; mi++)
            #pragma unroll
            for (int r = 0; r < 4; r++)
                p[mi][r] += __shfl_xor(p[mi][r], off);
    if (lm == 0) {
        #pragma unroll
        for (int mi = 0; mi < 4; mi++)
            #pragma unroll
            for (int r = 0; r < 4; r++)
                red[wc * BM + wr * 64 + mi * 16 + kq * 4 + r] = p[mi][r];
    }
    __syncthreads();
    if (tid < BM) {
        float s = red[tid] + red[BM + tid] + red[2 * BM + tid] + red[3 * BM + tid];
        s = fminf(s, 80.f);              // safety: exp stays finite
        float e = __expf(s);
        attn_out[b * SS + srow + tid] = e;   // unnormalized; k_finish scales
        esh[tid] = e;
        float rs = e;
        #pragma unroll
        for (int off = 32; off; off >>= 1) rs += __shfl_xor(rs, off);
        if ((tid & 63) == 0) dsum[tid >> 6] = rs;
    }
    __syncthreads();
    if (tid == 0) atomicAdd(den + b, dsum[0] + dsum[1]);

    // context partial: part[2*bx+half][d] = sum_{m in half} e_m * enc[m][d]
    const int half = tid >> 8;           // 0..1 -> rows half*64..+63
    const int c4   = tid & 255;          // float4 column
    const float4* e4 = (const float4*)(enc + (size_t)(m0 + half * 64) * DD) + c4;
    float4 a = {0.f, 0.f, 0.f, 0.f};
    #pragma unroll 8
    for (int j = 0; j < 64; j++) {
        float w = esh[half * 64 + j];
        float4 ev = e4[(size_t)j * (DD / 4)];
        a.x += w * ev.x; a.y += w * ev.y;
        a.z += w * ev.z; a.w += w * ev.w;
    }
    *(float4*)(part + (size_t)(blockIdx.x * 2 + half) * DD + c4 * 4) = a;
}

// ---------------- finish: ctx reduce + weight normalize ----------------------
__global__ __launch_bounds__(256) void k_finish(const float* __restrict__ part,
                                                const float* __restrict__ den,
                                                float* __restrict__ ctx,
                                                float* __restrict__ attn) {
    int b = blockIdx.x, y = blockIdx.y, t = threadIdx.x;
    float inv = 1.f / den[b];
    if (y < 4) {
        int d = y * 256 + t;
        float s = 0.f;
        #pragma unroll
        for (int j = 0; j < 32; j++) s += part[(size_t)(b * 32 + j) * DD + d];
        ctx[b * DD + d] = s * inv;
    } else {
        int sid = (y - 4) * 256 + t;
        attn[b * SS + sid] *= inv;
    }
}

extern "C" void kernel_launch(void* const* d_in, const int* in_sizes, int n_in,
                              void* d_out, int out_size, void* d_ws, size_t ws_size,
                              hipStream_t stream) {
    const float* hidden = (const float*)d_in[0];   // (L,B,D)
    const float* enc    = (const float*)d_in[1];   // (B,S,D)
    const float* attn_w = (const float*)d_in[2];   // (H,4H)
    const float* attn_b = (const float*)d_in[3];   // (H,)
    const float* v_w    = (const float*)d_in[4];   // (1,H)

    float* out      = (float*)d_out;
    float* ctx_out  = out;               // (B,1,D)
    float* attn_out = out + BB * DD;     // (B,1,S)

    float* base = (float*)d_ws;                                // B*H
    float* den  = base + BB * HH;                              // 32 (+pad)
    unsigned short* Bp = (unsigned short*)(den + 64);          // H*D bf16 (1 MB)
    float* part = (float*)(Bp + (size_t)HH * DD);              // 1024*D (4 MB)

    hipLaunchKernelGGL(k_pack, dim3(HH), dim3(256), 0, stream, attn_w, Bp, den);
    hipLaunchKernelGGL(k_base, dim3(BB * HH / 4), dim3(256), 0, stream,
                       hidden, attn_w, attn_b, base);
    hipLaunchKernelGGL(k_scores, dim3(BB * SS / BM), dim3(512), 0, stream,
                       enc, Bp, base, v_w, den, part, attn_out);
    hipLaunchKernelGGL(k_finish, dim3(BB, 12), dim3(256), 0, stream,
                       part, den, ctx_out, attn_out);
}